// Round 1
// baseline (306.032 us; speedup 1.0000x reference)
//
#include <hip/hip_runtime.h>

typedef __attribute__((ext_vector_type(8))) short short8;
typedef __attribute__((ext_vector_type(4))) float f32x4;

__device__ __forceinline__ short f2bf(float f) {
  unsigned u = __builtin_bit_cast(unsigned, f);
  u += 0x7fff + ((u >> 16) & 1);   // RNE
  return (short)(u >> 16);
}

// ---------------- weight fp32 -> bf16 ----------------
__global__ __launch_bounds__(256) void cvt4(const float* __restrict__ src,
                                            short* __restrict__ dst, int n) {
  int i = (blockIdx.x * 256 + threadIdx.x) * 4;
  if (i + 3 < n) {
#pragma unroll
    for (int j = 0; j < 4; ++j) dst[i + j] = f2bf(src[i + j]);
  }
}

// ---------------- per-head projection: Out = X @ W^T (bf16 MFMA) ----------------
// X: [65536, 64] fp32 (contiguous per head), Wb: [64][64] bf16.
// transpose==0: Out[row][col] bf16 ([BH*S, 64]); transpose==1: Out = [BH][64][2048] (V^T per head)
__global__ __launch_bounds__(256) void proj64(const float* __restrict__ X,
                                              const short* __restrict__ Wb,
                                              short* __restrict__ Out, int transpose) {
  __shared__ short xt[64][72];
  __shared__ short ot[64][72];
  const int tid = threadIdx.x;
  const int r0 = blockIdx.x * 64;
  const int row = tid >> 2, seg = (tid & 3) << 4;

  const float* src = X + (r0 + row) * 64 + seg;
  short8 v0, v1;
#pragma unroll
  for (int i = 0; i < 8; ++i) { v0[i] = f2bf(src[i]); v1[i] = f2bf(src[8 + i]); }
  *(short8*)&xt[row][seg] = v0;
  *(short8*)&xt[row][seg + 8] = v1;
  __syncthreads();

  const int lane = tid & 63, wave = tid >> 6;
  const int m16 = lane & 15, quad = lane >> 4;

  short8 a0 = *(const short8*)&xt[wave * 16 + m16][quad * 8];
  short8 a1 = *(const short8*)&xt[wave * 16 + m16][32 + quad * 8];

  f32x4 acc[4];
#pragma unroll
  for (int nt = 0; nt < 4; ++nt) {
    short8 b0 = *(const short8*)&Wb[(nt * 16 + m16) * 64 + quad * 8];
    short8 b1 = *(const short8*)&Wb[(nt * 16 + m16) * 64 + 32 + quad * 8];
    f32x4 z = (f32x4){0.f, 0.f, 0.f, 0.f};
    z = __builtin_amdgcn_mfma_f32_16x16x32_bf16(a0, b0, z, 0, 0, 0);
    z = __builtin_amdgcn_mfma_f32_16x16x32_bf16(a1, b1, z, 0, 0, 0);
    acc[nt] = z;
  }

  if (!transpose) {
#pragma unroll
    for (int nt = 0; nt < 4; ++nt)
#pragma unroll
      for (int r = 0; r < 4; ++r)
        Out[(r0 + wave * 16 + quad * 4 + r) * 64 + nt * 16 + m16] = f2bf(acc[nt][r]);
  } else {
#pragma unroll
    for (int nt = 0; nt < 4; ++nt)
#pragma unroll
      for (int r = 0; r < 4; ++r)
        ot[wave * 16 + quad * 4 + r][nt * 16 + m16] = f2bf(acc[nt][r]);
    __syncthreads();
    const int bh = r0 >> 11, s0 = r0 & 2047;
    const int d = tid >> 2, ch = (tid & 3) << 4;
    short8 w0, w1;
#pragma unroll
    for (int i = 0; i < 8; ++i) { w0[i] = ot[ch + i][d]; w1[i] = ot[ch + 8 + i][d]; }
    *(short8*)&Out[bh * 131072 + d * 2048 + s0 + ch] = w0;
    *(short8*)&Out[bh * 131072 + d * 2048 + s0 + ch + 8] = w1;
  }
}

// ---------------- flash attention ----------------
// Qp,Kp: [BH][2048][64] bf16; Vt: [BH][64][2048] bf16; mask: [B][2048][2048] int32
// O: [BH][2048][64] bf16.  64 q-rows per block (4 waves x 16 rows), 64-key tiles.
__global__ __launch_bounds__(256) void flash64(const short* __restrict__ Qp,
                                               const short* __restrict__ Kp,
                                               const short* __restrict__ Vt,
                                               const int* __restrict__ mask,
                                               short* __restrict__ O) {
  __shared__ short kt[64][72];
  __shared__ short vt[64][72];
  __shared__ short pt[64][72];
  const int tid = threadIdx.x;
  const int bid = blockIdx.x;
  const int bh = bid >> 5, qt = bid & 31;
  const int b = bh >> 4;
  const int q0 = qt << 6;
  const short* Qh = Qp + bh * 131072;
  const short* Kh = Kp + bh * 131072;
  const short* Vh = Vt + bh * 131072;
  const int* mb = mask + b * 4194304;
  const int lane = tid & 63, wave = tid >> 6;
  const int m16 = lane & 15, quad = lane >> 4;
  const int row = tid >> 2, seg = (tid & 3) << 4;

  const short8 aq0 = *(const short8*)&Qh[(q0 + wave * 16 + m16) * 64 + quad * 8];
  const short8 aq1 = *(const short8*)&Qh[(q0 + wave * 16 + m16) * 64 + 32 + quad * 8];

  float mrow[4], lrow[4];
  f32x4 oacc[4];
#pragma unroll
  for (int r = 0; r < 4; ++r) { mrow[r] = -3.0e38f; lrow[r] = 0.f; }
#pragma unroll
  for (int d = 0; d < 4; ++d) oacc[d] = (f32x4){0.f, 0.f, 0.f, 0.f};

  const float SC = 0.04508422f;  // log2(e) / 32  (softmax scale 1/sqrt(1024))

  for (int kti = 0; kti < 32; ++kti) {
    const int k0 = kti << 6;
    __syncthreads();
    *(short8*)&kt[row][seg] = *(const short8*)&Kh[(k0 + row) * 64 + seg];
    *(short8*)&kt[row][seg + 8] = *(const short8*)&Kh[(k0 + row) * 64 + seg + 8];
    *(short8*)&vt[row][seg] = *(const short8*)&Vh[row * 2048 + k0 + seg];
    *(short8*)&vt[row][seg + 8] = *(const short8*)&Vh[row * 2048 + k0 + seg + 8];
    __syncthreads();

    // S = Q K^T  (C-layout: col = key = lane&15 (+16*nt), row = q = quad*4+reg)
    f32x4 s[4];
#pragma unroll
    for (int nt = 0; nt < 4; ++nt) {
      short8 b0 = *(const short8*)&kt[nt * 16 + m16][quad * 8];
      short8 b1 = *(const short8*)&kt[nt * 16 + m16][32 + quad * 8];
      f32x4 z = (f32x4){0.f, 0.f, 0.f, 0.f};
      z = __builtin_amdgcn_mfma_f32_16x16x32_bf16(aq0, b0, z, 0, 0, 0);
      z = __builtin_amdgcn_mfma_f32_16x16x32_bf16(aq1, b1, z, 0, 0, 0);
      s[nt] = z;
    }

    // mask + scale into log2 domain
    float t[4][4];
#pragma unroll
    for (int r = 0; r < 4; ++r) {
      const int* mr = mb + (q0 + wave * 16 + quad * 4 + r) * 2048 + k0;
#pragma unroll
      for (int nt = 0; nt < 4; ++nt)
        t[nt][r] = mr[nt * 16 + m16] ? s[nt][r] * SC : -1.0e30f;
    }

    // online softmax (rows live in 16-lane quad groups; reduce with width-16 shuffles)
    float al[4];
#pragma unroll
    for (int r = 0; r < 4; ++r) {
      float mt = fmaxf(fmaxf(t[0][r], t[1][r]), fmaxf(t[2][r], t[3][r]));
#pragma unroll
      for (int off = 1; off < 16; off <<= 1) mt = fmaxf(mt, __shfl_xor(mt, off, 16));
      float mn = fmaxf(mrow[r], mt);
      al[r] = exp2f(mrow[r] - mn);
      mrow[r] = mn;
    }

    float p[4][4];
#pragma unroll
    for (int r = 0; r < 4; ++r) {
      float rs = 0.f;
#pragma unroll
      for (int nt = 0; nt < 4; ++nt) { p[nt][r] = exp2f(t[nt][r] - mrow[r]); rs += p[nt][r]; }
#pragma unroll
      for (int off = 1; off < 16; off <<= 1) rs += __shfl_xor(rs, off, 16);
      lrow[r] = lrow[r] * al[r] + rs;
    }
#pragma unroll
    for (int d = 0; d < 4; ++d)
#pragma unroll
      for (int r = 0; r < 4; ++r) oacc[d][r] *= al[r];

    // P: C-layout -> A-layout via wave-private LDS rows (same-wave DS is in-order; no barrier)
#pragma unroll
    for (int nt = 0; nt < 4; ++nt)
#pragma unroll
      for (int r = 0; r < 4; ++r)
        pt[wave * 16 + quad * 4 + r][nt * 16 + m16] = f2bf(p[nt][r]);

    short8 ap0 = *(const short8*)&pt[wave * 16 + m16][quad * 8];
    short8 ap1 = *(const short8*)&pt[wave * 16 + m16][32 + quad * 8];
#pragma unroll
    for (int dt = 0; dt < 4; ++dt) {
      short8 b0 = *(const short8*)&vt[dt * 16 + m16][quad * 8];
      short8 b1 = *(const short8*)&vt[dt * 16 + m16][32 + quad * 8];
      f32x4 z = oacc[dt];
      z = __builtin_amdgcn_mfma_f32_16x16x32_bf16(ap0, b0, z, 0, 0, 0);
      z = __builtin_amdgcn_mfma_f32_16x16x32_bf16(ap1, b1, z, 0, 0, 0);
      oacc[dt] = z;
    }
  }

#pragma unroll
  for (int r = 0; r < 4; ++r) {
    float inv = 1.0f / lrow[r];
#pragma unroll
    for (int dt = 0; dt < 4; ++dt)
      O[(bh * 2048 + q0 + wave * 16 + quad * 4 + r) * 64 + dt * 16 + m16] =
          f2bf(oacc[dt][r] * inv);
  }
}

// ---------------- final projection: out = O @ Wo^T + bo (fp32 out) ----------------
// O (as bf16): [4096][1024]; Wob: [1024][1024] bf16; out: [4096][1024] fp32
__global__ __launch_bounds__(256) void outproj(const short* __restrict__ Ob,
                                               const short* __restrict__ Wob,
                                               const float* __restrict__ bo,
                                               float* __restrict__ out) {
  __shared__ short at[64][72];
  __shared__ short bt[64][72];
  const int tid = threadIdx.x;
  const int bid = blockIdx.x;
  const int ct = bid & 15, rt = bid >> 4;
  const int r0 = rt * 64, c0 = ct * 64;
  const int lane = tid & 63, wave = tid >> 6;
  const int m16 = lane & 15, quad = lane >> 4;
  const int row = tid >> 2, seg = (tid & 3) << 4;

  f32x4 acc[4];
#pragma unroll
  for (int nt = 0; nt < 4; ++nt) acc[nt] = (f32x4){0.f, 0.f, 0.f, 0.f};

  for (int kc = 0; kc < 16; ++kc) {
    __syncthreads();
    *(short8*)&at[row][seg] = *(const short8*)&Ob[(r0 + row) * 1024 + kc * 64 + seg];
    *(short8*)&at[row][seg + 8] = *(const short8*)&Ob[(r0 + row) * 1024 + kc * 64 + seg + 8];
    *(short8*)&bt[row][seg] = *(const short8*)&Wob[(c0 + row) * 1024 + kc * 64 + seg];
    *(short8*)&bt[row][seg + 8] = *(const short8*)&Wob[(c0 + row) * 1024 + kc * 64 + seg + 8];
    __syncthreads();

    short8 a0 = *(const short8*)&at[wave * 16 + m16][quad * 8];
    short8 a1 = *(const short8*)&at[wave * 16 + m16][32 + quad * 8];
#pragma unroll
    for (int nt = 0; nt < 4; ++nt) {
      short8 b0 = *(const short8*)&bt[nt * 16 + m16][quad * 8];
      short8 b1 = *(const short8*)&bt[nt * 16 + m16][32 + quad * 8];
      f32x4 z = acc[nt];
      z = __builtin_amdgcn_mfma_f32_16x16x32_bf16(a0, b0, z, 0, 0, 0);
      z = __builtin_amdgcn_mfma_f32_16x16x32_bf16(a1, b1, z, 0, 0, 0);
      acc[nt] = z;
    }
  }

#pragma unroll
  for (int nt = 0; nt < 4; ++nt) {
    float bias = bo[c0 + nt * 16 + m16];
#pragma unroll
    for (int r = 0; r < 4; ++r)
      out[(r0 + wave * 16 + quad * 4 + r) * 1024 + c0 + nt * 16 + m16] = acc[nt][r] + bias;
  }
}

// ---------------- launch ----------------
extern "C" void kernel_launch(void* const* d_in, const int* in_sizes, int n_in,
                              void* d_out, int out_size, void* d_ws, size_t ws_size,
                              hipStream_t stream) {
  const float* query = (const float*)d_in[0];
  const float* key = (const float*)d_in[1];
  const float* value = (const float*)d_in[2];
  const int* mask = (const int*)d_in[3];
  const float* Wq = (const float*)d_in[4];
  const float* Wk = (const float*)d_in[5];
  const float* Wv = (const float*)d_in[6];
  const float* Wo = (const float*)d_in[7];
  const float* bo = (const float*)d_in[8];
  float* out = (float*)d_out;

  char* ws = (char*)d_ws;
  // ws layout (bytes): Qp 0..8M, Kp 8M..16M, Vt 16M..24M, Ob 24M..32M(@25165824),
  // Wob @33554432 (2MB), Wqb/Wkb/Wvb @35651584+
  short* Qp = (short*)(ws);
  short* Kp = (short*)(ws + 8388608);
  short* Vt = (short*)(ws + 16777216);
  short* Ob = (short*)(ws + 25165824);
  short* Wob = (short*)(ws + 33554432);
  short* Wqb = (short*)(ws + 35651584);
  short* Wkb = (short*)(ws + 35659776);
  short* Wvb = (short*)(ws + 35667968);

  cvt4<<<1024, 256, 0, stream>>>(Wo, Wob, 1048576);
  cvt4<<<4, 256, 0, stream>>>(Wq, Wqb, 4096);
  cvt4<<<4, 256, 0, stream>>>(Wk, Wkb, 4096);
  cvt4<<<4, 256, 0, stream>>>(Wv, Wvb, 4096);

  proj64<<<1024, 256, 0, stream>>>(query, Wqb, Qp, 0);
  proj64<<<1024, 256, 0, stream>>>(key, Wkb, Kp, 0);
  proj64<<<1024, 256, 0, stream>>>(value, Wvb, Vt, 1);

  flash64<<<1024, 256, 0, stream>>>(Qp, Kp, Vt, mask, Ob);

  outproj<<<1024, 256, 0, stream>>>(Ob, Wob, bo, out);
}

// Round 2
// 246.883 us; speedup vs baseline: 1.2396x; 1.2396x over previous
//
#include <hip/hip_runtime.h>

typedef __attribute__((ext_vector_type(8))) short short8;
typedef __attribute__((ext_vector_type(4))) float f32x4;
typedef __attribute__((ext_vector_type(2))) int int2v;

__device__ __forceinline__ short f2bf(float f) {
  unsigned u = __builtin_bit_cast(unsigned, f);
  u += 0x7fff + ((u >> 16) & 1);  // RNE
  return (short)(u >> 16);
}

// pack two floats -> two bf16 in one int (lo = first arg)
__device__ __forceinline__ int pk2bf(float lo, float hi) {
#if defined(__gfx950__) && __has_builtin(__builtin_amdgcn_cvt_pk_bf16_f32)
  typedef __attribute__((ext_vector_type(2))) __bf16 bf16x2;
  bf16x2 v = __builtin_amdgcn_cvt_pk_bf16_f32(lo, hi);
  return __builtin_bit_cast(int, v);
#else
  return (int)(unsigned short)(short)f2bf(lo) | (((int)f2bf(hi)) << 16);
#endif
}

__device__ __forceinline__ float fand(float p, int m) {
  return __builtin_bit_cast(float, __builtin_bit_cast(int, p) & m);
}

__device__ __forceinline__ int bmask(unsigned nib, int bit) {
#if __has_builtin(__builtin_amdgcn_sbfe)
  return __builtin_amdgcn_sbfe((int)nib, bit, 1);  // 0 or 0xFFFFFFFF
#else
  return -(int)((nib >> bit) & 1);
#endif
}

__device__ __forceinline__ float fexp2(float x) {
#if __has_builtin(__builtin_amdgcn_exp2f)
  return __builtin_amdgcn_exp2f(x);
#else
  return exp2f(x);
#endif
}

// ---------------- all weights fp32 -> bf16, one dispatch ----------------
__global__ __launch_bounds__(256) void cvtall(const float* __restrict__ Wo,
                                              const float* __restrict__ Wq,
                                              const float* __restrict__ Wk,
                                              const float* __restrict__ Wv,
                                              short* __restrict__ Wob,
                                              short* __restrict__ Wqb,
                                              short* __restrict__ Wkb,
                                              short* __restrict__ Wvb) {
  int bid = blockIdx.x;
  const float* s;
  short* d;
  int base;
  if (bid < 1024) { s = Wo; d = Wob; base = bid; }
  else if (bid < 1028) { s = Wq; d = Wqb; base = bid - 1024; }
  else if (bid < 1032) { s = Wk; d = Wkb; base = bid - 1028; }
  else { s = Wv; d = Wvb; base = bid - 1032; }
  int i = (base * 256 + threadIdx.x) * 4;
#pragma unroll
  for (int j = 0; j < 4; ++j) d[i + j] = f2bf(s[i + j]);
}

// ---------------- mask bit-pack with sigma permutation ----------------
// word w for (b,row,kt): bit j = (mask[b][row][kt*64 + sigma^-1(j)] != 0),
// sigma(k) = 4*(k&15) + (k>>4), sigma^-1(j) = (j&3)*16 + (j>>2)
__global__ __launch_bounds__(256) void packmask(const int* __restrict__ mask,
                                                unsigned long long* __restrict__ mpk) {
  int gid = blockIdx.x * 256 + threadIdx.x;
  int base = gid & ~63;
  int j = gid & 63;
  int v = mask[base + ((j & 3) << 4) + (j >> 2)];
  unsigned long long bal = __ballot(v != 0);
  if (j == 0) mpk[gid >> 6] = bal;
}

// ---------------- fused head projections (Q: pre-scaled; V: sigma-permuted V^T) ----
// mode 0: Qp = (q @ Wq^T) * log2e/32, [BH*S,64]
// mode 1: Kp =  k @ Wk^T,             [BH*S,64]
// mode 2: Vt = (v @ Wv^T)^T per head, [BH][64][2048], columns sigma-permuted per 64
__global__ __launch_bounds__(256) void projall(const float* __restrict__ q,
                                               const float* __restrict__ k,
                                               const float* __restrict__ v,
                                               const short* __restrict__ Wqb,
                                               const short* __restrict__ Wkb,
                                               const short* __restrict__ Wvb,
                                               short* __restrict__ Qp,
                                               short* __restrict__ Kp,
                                               short* __restrict__ Vtp) {
  __shared__ short xt[64][72];
  __shared__ short ot[64][72];
  const int mode = blockIdx.x >> 10;
  const int bid = blockIdx.x & 1023;
  const float* X;
  const short* Wb;
  short* Out;
  float scale;
  if (mode == 0) { X = q; Wb = Wqb; Out = Qp; scale = 0.045084220f; }
  else if (mode == 1) { X = k; Wb = Wkb; Out = Kp; scale = 1.0f; }
  else { X = v; Wb = Wvb; Out = Vtp; scale = 1.0f; }

  const int tid = threadIdx.x;
  const int r0 = bid * 64;
  const int row = tid >> 2, seg = (tid & 3) << 4;

  const float* src = X + (r0 + row) * 64 + seg;
  short8 v0, v1;
#pragma unroll
  for (int i = 0; i < 8; ++i) { v0[i] = f2bf(src[i]); v1[i] = f2bf(src[8 + i]); }
  *(short8*)&xt[row][seg] = v0;
  *(short8*)&xt[row][seg + 8] = v1;
  __syncthreads();

  const int lane = tid & 63, wave = tid >> 6;
  const int m16 = lane & 15, quad = lane >> 4;

  short8 a0 = *(const short8*)&xt[wave * 16 + m16][quad * 8];
  short8 a1 = *(const short8*)&xt[wave * 16 + m16][32 + quad * 8];

  f32x4 acc[4];
#pragma unroll
  for (int nt = 0; nt < 4; ++nt) {
    short8 b0 = *(const short8*)&Wb[(nt * 16 + m16) * 64 + quad * 8];
    short8 b1 = *(const short8*)&Wb[(nt * 16 + m16) * 64 + 32 + quad * 8];
    f32x4 z = (f32x4){0.f, 0.f, 0.f, 0.f};
    z = __builtin_amdgcn_mfma_f32_16x16x32_bf16(a0, b0, z, 0, 0, 0);
    z = __builtin_amdgcn_mfma_f32_16x16x32_bf16(a1, b1, z, 0, 0, 0);
    acc[nt] = z;
  }

  if (mode != 2) {
#pragma unroll
    for (int nt = 0; nt < 4; ++nt)
#pragma unroll
      for (int r = 0; r < 4; ++r)
        Out[(r0 + wave * 16 + quad * 4 + r) * 64 + nt * 16 + m16] = f2bf(acc[nt][r] * scale);
  } else {
#pragma unroll
    for (int nt = 0; nt < 4; ++nt)
#pragma unroll
      for (int r = 0; r < 4; ++r)
        ot[wave * 16 + quad * 4 + r][nt * 16 + m16] = f2bf(acc[nt][r]);
    __syncthreads();
    // write V^T with sigma-permuted columns: local key l -> s0 + 4*(l&15) + (l>>4)
    const int bh = r0 >> 11, s0 = r0 & 2047;
    const int d = tid >> 2, c4 = tid & 3;  // l = c4*16 + i  ->  sigma = 4*i + c4
    short* ob = Out + bh * 131072 + d * 2048 + s0 + c4;
#pragma unroll
    for (int i = 0; i < 16; ++i) ob[4 * i] = ot[c4 * 16 + i][d];
  }
}

// ---------------- flash attention, no-max softmax, packed mask ----------------
// Qp (pre-scaled): [BH][2048][64]; Kp: [BH][2048][64]; Vt: [BH][64][2048] sigma-ordered;
// mpk: [B][2048][32] uint64 sigma-ordered bits; O: [BH][2048][64] bf16
__global__ __launch_bounds__(256) void flash64(const short* __restrict__ Qp,
                                               const short* __restrict__ Kp,
                                               const short* __restrict__ Vt,
                                               const unsigned long long* __restrict__ mpk,
                                               short* __restrict__ O) {
  __shared__ short kt[64][72];
  __shared__ short vt[64][72];
  __shared__ __attribute__((aligned(16))) short pt[64][72];
  const int tid = threadIdx.x;
  const int bid = blockIdx.x;
  const int bh = bid >> 5, qt = bid & 31;
  const int b = bh >> 4;
  const int q0 = qt << 6;
  const short* Qh = Qp + bh * 131072;
  const short* Kh = Kp + bh * 131072;
  const short* Vh = Vt + bh * 131072;
  const int lane = tid & 63, wave = tid >> 6;
  const int m16 = lane & 15, quad = lane >> 4;
  const int row = tid >> 2, seg = (tid & 3) << 4;
  const int prow = wave * 16 + quad * 4;  // first of this lane's 4 q-rows in tile
  const unsigned long long* mrow = mpk + (b * 2048 + q0 + prow) * 32;
  const int msh = m16 * 4;

  const short8 aq0 = *(const short8*)&Qh[(q0 + wave * 16 + m16) * 64 + quad * 8];
  const short8 aq1 = *(const short8*)&Qh[(q0 + wave * 16 + m16) * 64 + 32 + quad * 8];

  float lrow[4] = {0.f, 0.f, 0.f, 0.f};
  f32x4 oacc[4];
#pragma unroll
  for (int d = 0; d < 4; ++d) oacc[d] = (f32x4){0.f, 0.f, 0.f, 0.f};

  for (int kti = 0; kti < 32; ++kti) {
    const int k0 = kti << 6;
    __syncthreads();
    *(short8*)&kt[row][seg] = *(const short8*)&Kh[(k0 + row) * 64 + seg];
    *(short8*)&kt[row][seg + 8] = *(const short8*)&Kh[(k0 + row) * 64 + seg + 8];
    *(short8*)&vt[row][seg] = *(const short8*)&Vh[row * 2048 + k0 + seg];
    *(short8*)&vt[row][seg + 8] = *(const short8*)&Vh[row * 2048 + k0 + seg + 8];
    __syncthreads();

    // S = Q K^T (scaled; C-layout col = k = nt*16+m16, row = q = quad*4+r)
    f32x4 s[4];
#pragma unroll
    for (int nt = 0; nt < 4; ++nt) {
      short8 b0 = *(const short8*)&kt[nt * 16 + m16][quad * 8];
      short8 b1 = *(const short8*)&kt[nt * 16 + m16][32 + quad * 8];
      f32x4 z = (f32x4){0.f, 0.f, 0.f, 0.f};
      z = __builtin_amdgcn_mfma_f32_16x16x32_bf16(aq0, b0, z, 0, 0, 0);
      z = __builtin_amdgcn_mfma_f32_16x16x32_bf16(aq1, b1, z, 0, 0, 0);
      s[nt] = z;
    }

    // mask nibbles: element (nt,m16) <-> bit 4*m16+nt of the row's word
    unsigned nib[4];
#pragma unroll
    for (int r = 0; r < 4; ++r) {
      unsigned long long w = mrow[r * 32 + kti];
      nib[r] = (unsigned)(w >> msh) & 15u;
    }

    // p = exp2(s) & mask; accumulate per-lane l; write P (bf16, sigma cols) to LDS
#pragma unroll
    for (int r = 0; r < 4; ++r) {
      float p0 = fand(fexp2(s[0][r]), bmask(nib[r], 0));
      float p1 = fand(fexp2(s[1][r]), bmask(nib[r], 1));
      float p2 = fand(fexp2(s[2][r]), bmask(nib[r], 2));
      float p3 = fand(fexp2(s[3][r]), bmask(nib[r], 3));
      lrow[r] += (p0 + p1) + (p2 + p3);
      int2v pp;
      pp.x = pk2bf(p0, p1);
      pp.y = pk2bf(p2, p3);
      *(int2v*)&pt[prow + r][msh] = pp;  // 4 bf16 at sigma cols 4*m16..+3 (b64)
    }

    // P(A-layout, storage order) x V'(storage order) -> O
    short8 ap0 = *(const short8*)&pt[wave * 16 + m16][quad * 8];
    short8 ap1 = *(const short8*)&pt[wave * 16 + m16][32 + quad * 8];
#pragma unroll
    for (int dt = 0; dt < 4; ++dt) {
      short8 b0 = *(const short8*)&vt[dt * 16 + m16][quad * 8];
      short8 b1 = *(const short8*)&vt[dt * 16 + m16][32 + quad * 8];
      f32x4 z = oacc[dt];
      z = __builtin_amdgcn_mfma_f32_16x16x32_bf16(ap0, b0, z, 0, 0, 0);
      z = __builtin_amdgcn_mfma_f32_16x16x32_bf16(ap1, b1, z, 0, 0, 0);
      oacc[dt] = z;
    }
  }

  // one-time l reduction across the 16 lanes holding each row
#pragma unroll
  for (int r = 0; r < 4; ++r) {
#pragma unroll
    for (int off = 1; off < 16; off <<= 1) lrow[r] += __shfl_xor(lrow[r], off, 16);
  }

#pragma unroll
  for (int r = 0; r < 4; ++r) {
    float inv = 1.0f / lrow[r];
#pragma unroll
    for (int dt = 0; dt < 4; ++dt)
      O[(bh * 2048 + q0 + wave * 16 + quad * 4 + r) * 64 + dt * 16 + m16] =
          f2bf(oacc[dt][r] * inv);
  }
}

// ---------------- final projection: out = O @ Wo^T + bo, 128x128 tiles ----------------
__global__ __launch_bounds__(256) void outproj(const short* __restrict__ Ob,
                                               const short* __restrict__ Wob,
                                               const float* __restrict__ bo,
                                               float* __restrict__ out) {
  __shared__ short at[128][72];
  __shared__ short bt[128][72];
  const int tid = threadIdx.x;
  const int bid = blockIdx.x;
  const int ct = bid & 7, rt = bid >> 3;
  const int r0 = rt * 128, c0 = ct * 128;
  const int lane = tid & 63, wave = tid >> 6;
  const int wr = (wave >> 1) * 64, wc = (wave & 1) * 64;
  const int m16 = lane & 15, quad = lane >> 4;
  const int srow = tid >> 1, shalf = (tid & 1) * 32;

  f32x4 acc[4][4];
#pragma unroll
  for (int mt = 0; mt < 4; ++mt)
#pragma unroll
    for (int nt = 0; nt < 4; ++nt) acc[mt][nt] = (f32x4){0.f, 0.f, 0.f, 0.f};

  for (int kc = 0; kc < 16; ++kc) {
    __syncthreads();
    const short* ag = &Ob[(r0 + srow) * 1024 + kc * 64 + shalf];
    const short* bg = &Wob[(c0 + srow) * 1024 + kc * 64 + shalf];
    *(short8*)&at[srow][shalf] = *(const short8*)&ag[0];
    *(short8*)&at[srow][shalf + 8] = *(const short8*)&ag[8];
    *(short8*)&at[srow][shalf + 16] = *(const short8*)&ag[16];
    *(short8*)&at[srow][shalf + 24] = *(const short8*)&ag[24];
    *(short8*)&bt[srow][shalf] = *(const short8*)&bg[0];
    *(short8*)&bt[srow][shalf + 8] = *(const short8*)&bg[8];
    *(short8*)&bt[srow][shalf + 16] = *(const short8*)&bg[16];
    *(short8*)&bt[srow][shalf + 24] = *(const short8*)&bg[24];
    __syncthreads();

#pragma unroll
    for (int kh = 0; kh < 2; ++kh) {
      short8 af[4], bf[4];
#pragma unroll
      for (int i = 0; i < 4; ++i) {
        af[i] = *(const short8*)&at[wr + i * 16 + m16][kh * 32 + quad * 8];
        bf[i] = *(const short8*)&bt[wc + i * 16 + m16][kh * 32 + quad * 8];
      }
#pragma unroll
      for (int mt = 0; mt < 4; ++mt)
#pragma unroll
        for (int nt = 0; nt < 4; ++nt)
          acc[mt][nt] = __builtin_amdgcn_mfma_f32_16x16x32_bf16(af[mt], bf[nt], acc[mt][nt], 0, 0, 0);
    }
  }

#pragma unroll
  for (int nt = 0; nt < 4; ++nt) {
    const int col = c0 + wc + nt * 16 + m16;
    const float bias = bo[col];
#pragma unroll
    for (int mt = 0; mt < 4; ++mt)
#pragma unroll
      for (int rr = 0; rr < 4; ++rr)
        out[(r0 + wr + mt * 16 + quad * 4 + rr) * 1024 + col] = acc[mt][nt][rr] + bias;
  }
}

// ---------------- launch ----------------
extern "C" void kernel_launch(void* const* d_in, const int* in_sizes, int n_in,
                              void* d_out, int out_size, void* d_ws, size_t ws_size,
                              hipStream_t stream) {
  const float* query = (const float*)d_in[0];
  const float* key = (const float*)d_in[1];
  const float* value = (const float*)d_in[2];
  const int* mask = (const int*)d_in[3];
  const float* Wq = (const float*)d_in[4];
  const float* Wk = (const float*)d_in[5];
  const float* Wv = (const float*)d_in[6];
  const float* Wo = (const float*)d_in[7];
  const float* bo = (const float*)d_in[8];
  float* out = (float*)d_out;

  char* ws = (char*)d_ws;
  short* Qp = (short*)(ws);
  short* Kp = (short*)(ws + 8388608);
  short* Vt = (short*)(ws + 16777216);
  short* Ob = (short*)(ws + 25165824);
  short* Wob = (short*)(ws + 33554432);
  short* Wqb = (short*)(ws + 35651584);
  short* Wkb = (short*)(ws + 35659776);
  short* Wvb = (short*)(ws + 35667968);
  unsigned long long* mpk = (unsigned long long*)(ws + 35676160);  // 1 MB

  cvtall<<<1036, 256, 0, stream>>>(Wo, Wq, Wk, Wv, Wob, Wqb, Wkb, Wvb);
  packmask<<<32768, 256, 0, stream>>>(mask, mpk);
  projall<<<3072, 256, 0, stream>>>(query, key, value, Wqb, Wkb, Wvb, Qp, Kp, Vt);
  flash64<<<1024, 256, 0, stream>>>(Qp, Kp, Vt, mpk, Ob);
  outproj<<<256, 256, 0, stream>>>(Ob, Wob, bo, out);
}